// Round 4
// baseline (410.703 us; speedup 1.0000x reference)
//
#include <hip/hip_runtime.h>
#include <math.h>
#include <stdint.h>

// Problem constants
#define T_TOK 8192
#define D_DIM 7168
#define E_EXP 256
#define K_SEL 8
#define G_GRP 8
#define LG_GRP 4
#define ROUTE_SCALE 2.5f

// GEMM tiling: 128x128 block, BK=32, split-K=4, 256 threads (4 waves, 64x64/wave)
#define BKT 32
#define NKT32 (D_DIM / BKT)     // 224 k-tiles of 32
#define SPLITK 4
#define KT_SLICE (NKT32 / SPLITK)  // 56
#define SCALE_LO 2048.0f        // 2^11
#define INV_SCALE (1.0f / 2048.0f)

typedef _Float16 half_t;
typedef _Float16 half8 __attribute__((ext_vector_type(8)));
typedef float f32x4 __attribute__((ext_vector_type(4)));

__device__ __forceinline__ void load_lds16(const void* g, void* l) {
    __builtin_amdgcn_global_load_lds(
        (const __attribute__((address_space(1))) uint32_t*)g,
        (__attribute__((address_space(3))) uint32_t*)l, 16, 0, 0);
}

// ---------------------------------------------------------------------------
// Pre-pass: W[256][7168] fp32 -> Wf f16 hi/lo in BK=32 fragment-tile order.
// Tile(n,kt) = 16 KB = [section s=p*2+h (16)][slot (64)][8 halfs],
// slot encodes (col=slot&15, k-oct=slot>>4) for the 16x16x32 B fragment.
// ---------------------------------------------------------------------------
__global__ __launch_bounds__(256)
void convert_W_kernel(const float* __restrict__ W, half_t* __restrict__ Wf) {
    const int v = blockIdx.x * 256 + threadIdx.x;   // 0..229375
    const int slot = v & 63;
    const int p    = (v >> 6) & 7;
    const int rest = v >> 9;            // 0..447
    const int ktg  = rest % NKT32;      // 0..223
    const int n    = rest / NKT32;      // 0..1
    const int e = n * 128 + p * 16 + (slot & 15);
    const int k = ktg * BKT + (slot >> 4) * 8;

    const float* src = W + (size_t)e * D_DIM + k;
    float4 v0 = *(const float4*)src;
    float4 v1 = *(const float4*)(src + 4);
    float f[8] = {v0.x, v0.y, v0.z, v0.w, v1.x, v1.y, v1.z, v1.w};
    half8 hi, lo;
    #pragma unroll
    for (int j = 0; j < 8; j++) {
        const half_t h = (half_t)f[j];
        hi[j] = h;
        lo[j] = (half_t)((f[j] - (float)h) * SCALE_LO);
    }
    half_t* tile = Wf + ((size_t)(n * NKT32 + ktg)) * 8192;
    *(half8*)&tile[(p * 2 + 0) * 512 + slot * 8] = hi;
    *(half8*)&tile[(p * 2 + 1) * 512 + slot * 8] = lo;
}

// ---------------------------------------------------------------------------
// GEMM: partial logits, 3-term split-f16 MFMA, 128x128 tile, split-K=4.
// A staged raw fp32 via global_load_lds (section s=p*2+r: r=fp32 j 0-3 / 4-7),
// converted to f16 hi/lo per wave at fragment-read time. B from pre-converted
// Wf. Both buffers double-buffered; ONE barrier per kt: loads for t+1 issued
// before compute(t), drained at the next barrier (full-compute prefetch dist).
// ---------------------------------------------------------------------------
__global__ __launch_bounds__(256, 2)
void gemm_logits_f16split(const float* __restrict__ x,
                          const half_t* __restrict__ Wf,
                          float* __restrict__ planes) {
    __shared__ __align__(16) float  Abuf[2][4096];   // 2 x 16 KB fp32
    __shared__ __align__(16) half_t Bbuf[2][8192];   // 2 x 16 KB f16 hi/lo

    const int tid = threadIdx.x;
    const int bid = blockIdx.x;
    const int n    = bid & 1;
    const int sp   = (bid >> 1) & 3;
    const int mb   = bid >> 3;          // 0..63
    const int row0 = mb * 128;
    const int kt0  = sp * KT_SLICE;

    const float* __restrict__ xA = x + (size_t)row0 * D_DIM;
    float* __restrict__ plane = planes + (size_t)sp * T_TOK * E_EXP;

    const int wave = tid >> 6, lane = tid & 63;
    const int wm = wave >> 1, wn = wave & 1;
    const int np0 = wn * 4;
    const int q = lane >> 4;

    // per-wave issue: 4 A-sections + 4 B-sections per kt
    auto issue = [&](int t) {
        const int ktg = kt0 + t;
        const int b = t & 1;
        // A: section sa = wave*4+i = p*2+r
        #pragma unroll
        for (int i = 0; i < 4; i++) {
            const int sa = wave * 4 + i;
            const int p = sa >> 1, r = sa & 1;
            const float* src = xA + (size_t)(p * 16 + (lane & 15)) * D_DIM
                             + ktg * BKT + q * 8 + r * 4;
            load_lds16(src, &Abuf[b][sa * 256]);    // 256 floats per section
        }
        // B: section sb = wave*4+i, contiguous 1 KB from Wf tile
        const half_t* tile = Wf + ((size_t)(n * NKT32 + ktg)) * 8192;
        #pragma unroll
        for (int i = 0; i < 4; i++) {
            const int sb = wave * 4 + i;
            load_lds16(tile + sb * 512 + lane * 8, &Bbuf[b][sb * 512]);
        }
    };

    f32x4 ach[4][4] = {}, acx[4][4] = {};

    auto compute = [&](int t) {
        const int b = t & 1;
        half8 bh[4], bl[4];
        #pragma unroll
        for (int ni = 0; ni < 4; ni++) {
            const int p = np0 + ni;
            bh[ni] = *(const half8*)&Bbuf[b][(p * 2 + 0) * 512 + lane * 8];
            bl[ni] = *(const half8*)&Bbuf[b][(p * 2 + 1) * 512 + lane * 8];
        }
        half8 ah[4], al[4];
        #pragma unroll
        for (int mi = 0; mi < 4; mi++) {
            const int p = wm * 4 + mi;
            const float4 f0 = *(const float4*)&Abuf[b][((p * 2 + 0) * 64 + lane) * 4];
            const float4 f1 = *(const float4*)&Abuf[b][((p * 2 + 1) * 64 + lane) * 4];
            const float f[8] = {f0.x, f0.y, f0.z, f0.w, f1.x, f1.y, f1.z, f1.w};
            #pragma unroll
            for (int j = 0; j < 8; j++) {
                const half_t h = (half_t)f[j];
                ah[mi][j] = h;
                al[mi][j] = (half_t)((f[j] - (float)h) * SCALE_LO);
            }
        }
        #pragma unroll
        for (int mi = 0; mi < 4; mi++)
            #pragma unroll
            for (int ni = 0; ni < 4; ni++) {
                ach[mi][ni] = __builtin_amdgcn_mfma_f32_16x16x32_f16(ah[mi], bh[ni], ach[mi][ni], 0, 0, 0);
                acx[mi][ni] = __builtin_amdgcn_mfma_f32_16x16x32_f16(ah[mi], bl[ni], acx[mi][ni], 0, 0, 0);
                acx[mi][ni] = __builtin_amdgcn_mfma_f32_16x16x32_f16(al[mi], bh[ni], acx[mi][ni], 0, 0, 0);
            }
    };

    issue(0);
    #pragma unroll 1
    for (int t = 0; t < KT_SLICE; t++) {
        __syncthreads();                 // drains loads(t); guards buf reuse
        if (t + 1 < KT_SLICE) issue(t + 1);
        compute(t);
    }

    #pragma unroll
    for (int mi = 0; mi < 4; mi++)
        #pragma unroll
        for (int ni = 0; ni < 4; ni++) {
            const int ex = n * 128 + (np0 + ni) * 16 + (lane & 15);
            #pragma unroll
            for (int r = 0; r < 4; r++) {
                const int tok = row0 + (wm * 4 + mi) * 16 + q * 4 + r;
                plane[(size_t)tok * E_EXP + ex] =
                    ach[mi][ni][r] + acx[mi][ni][r] * INV_SCALE;
            }
        }
}

// ---------------------------------------------------------------------------
// Routing: one wave per token; sums the 4 split-K planes. No atomics.
// ---------------------------------------------------------------------------
__global__ __launch_bounds__(256)
void routing_kernel(const float* __restrict__ planes,
                    const float* __restrict__ bias,
                    float* __restrict__ out_w,
                    float* __restrict__ out_i) {
    const int wave = threadIdx.x >> 6;
    const int lane = threadIdx.x & 63;
    const int t    = blockIdx.x * 4 + wave;

    float lg[4] = {0.f, 0.f, 0.f, 0.f};
    #pragma unroll
    for (int spp = 0; spp < SPLITK; spp++) {
        const float4 l = *(const float4*)(planes + (size_t)spp * T_TOK * E_EXP
                                          + (size_t)t * E_EXP + lane * 4);
        lg[0] += l.x; lg[1] += l.y; lg[2] += l.z; lg[3] += l.w;
    }
    const float4 bi = *(const float4*)(bias + lane * 4);

    float orig[4], s[4];
    #pragma unroll
    for (int j = 0; j < 4; j++)
        orig[j] = 1.0f / (1.0f + expf(-lg[j]));
    s[0] = orig[0] + bi.x; s[1] = orig[1] + bi.y;
    s[2] = orig[2] + bi.z; s[3] = orig[3] + bi.w;

    float p1 = fmaxf(s[0], s[1]), p2 = fminf(s[0], s[1]);
    float q1 = fmaxf(s[2], s[3]), q2 = fminf(s[2], s[3]);
    float m1 = fmaxf(p1, q1);
    float m2 = fmaxf(fminf(p1, q1), (p1 >= q1) ? p2 : q2);

    #pragma unroll
    for (int off = 1; off <= 4; off <<= 1) {
        float o1 = __shfl_xor(m1, off);
        float o2 = __shfl_xor(m2, off);
        float M1 = fmaxf(m1, o1);
        float M2 = fmaxf(fminf(m1, o1), (m1 >= o1) ? m2 : o2);
        m1 = M1; m2 = M2;
    }
    const float gscore = m1 + m2;

    const int g = lane >> 3;
    int cnt = 0;
    #pragma unroll
    for (int j = 0; j < G_GRP; j++) {
        float gj = __shfl(gscore, j * 8);
        cnt += (gj > gscore || (gj == gscore && j < g)) ? 1 : 0;
    }
    const bool keep = (cnt < LG_GRP);

    float smask[4];
    #pragma unroll
    for (int j = 0; j < 4; j++) smask[j] = keep ? s[j] : -INFINITY;

    float wsum = 0.0f, my_o = 0.0f;
    int my_i = 0;

    #pragma unroll
    for (int k = 0; k < K_SEL; k++) {
        float bv = smask[0]; float bo = orig[0]; int bs = 0;
        if (smask[1] > bv) { bv = smask[1]; bo = orig[1]; bs = 1; }
        if (smask[2] > bv) { bv = smask[2]; bo = orig[2]; bs = 2; }
        if (smask[3] > bv) { bv = smask[3]; bo = orig[3]; bs = 3; }
        int bidx = lane * 4 + bs;

        #pragma unroll
        for (int off = 32; off >= 1; off >>= 1) {
            float ov = __shfl_xor(bv, off);
            float oo = __shfl_xor(bo, off);
            int   oi = __shfl_xor(bidx, off);
            if (ov > bv || (ov == bv && oi < bidx)) { bv = ov; bo = oo; bidx = oi; }
        }
        wsum += bo;
        if (lane == k) { my_o = bo; my_i = bidx; }
        if ((bidx >> 2) == lane) {
            const int sl = bidx & 3;
            smask[0] = (sl == 0) ? -INFINITY : smask[0];
            smask[1] = (sl == 1) ? -INFINITY : smask[1];
            smask[2] = (sl == 2) ? -INFINITY : smask[2];
            smask[3] = (sl == 3) ? -INFINITY : smask[3];
        }
    }

    if (lane < K_SEL) {
        out_w[(size_t)t * K_SEL + lane] = my_o * ROUTE_SCALE / wsum;
        out_i[(size_t)t * K_SEL + lane] = (float)my_i;
    }
}

// ---------------------------------------------------------------------------
// Counts: block e scans all T*K indices for expert e. L2-hot, zero atomics.
// ---------------------------------------------------------------------------
__global__ __launch_bounds__(256)
void count_kernel(const float* __restrict__ idxf, float* __restrict__ out_c) {
    const float fe = (float)blockIdx.x;
    int c = 0;
    const float4* p = (const float4*)idxf;
    for (int i = threadIdx.x; i < (T_TOK * K_SEL / 4); i += 256) {
        float4 v = p[i];
        c += (v.x == fe) + (v.y == fe) + (v.z == fe) + (v.w == fe);
    }
    __shared__ int red[4];
    #pragma unroll
    for (int off = 32; off >= 1; off >>= 1) c += __shfl_down(c, off);
    if ((threadIdx.x & 63) == 0) red[threadIdx.x >> 6] = c;
    __syncthreads();
    if (threadIdx.x == 0)
        out_c[blockIdx.x] = (float)(red[0] + red[1] + red[2] + red[3]);
}

// ---------------- launch ----------------
extern "C" void kernel_launch(void* const* d_in, const int* in_sizes, int n_in,
                              void* d_out, int out_size, void* d_ws, size_t ws_size,
                              hipStream_t stream) {
    const float* x    = (const float*)d_in[0];
    const float* W    = (const float*)d_in[1];
    const float* bias = (const float*)d_in[2];

    float* out   = (float*)d_out;
    float* out_w = out;
    float* out_i = out + (size_t)T_TOK * K_SEL;
    float* out_c = out + (size_t)2 * T_TOK * K_SEL;

    float* planes = (float*)d_ws;                                   // 4 x 8 MB
    half_t* Wf = (half_t*)(planes + (size_t)SPLITK * T_TOK * E_EXP); // 7.34 MB

    hipLaunchKernelGGL(convert_W_kernel, dim3(896), dim3(256), 0, stream, W, Wf);
    hipLaunchKernelGGL(gemm_logits_f16split, dim3(512), dim3(256), 0, stream,
                       x, Wf, planes);
    hipLaunchKernelGGL(routing_kernel, dim3(T_TOK / 4), dim3(256), 0, stream,
                       planes, bias, out_w, out_i);
    hipLaunchKernelGGL(count_kernel, dim3(E_EXP), dim3(256), 0, stream,
                       out_i, out_c);
}